// Round 8
// baseline (1498.907 us; speedup 1.0000x reference)
//
#include <hip/hip_runtime.h>
#include <math.h>

// Problem constants (fixed by the reference setup_inputs)
#define BATCH 32
#define CH    192
#define TFEAT 2048
#define TTXT  512
#define NEGINF (-1e9f)

#define ATTN_ELEMS ((size_t)BATCH * TFEAT * TTXT)   // 33,554,432
#define DUR_OFF    ATTN_ELEMS
#define NEG_OFF    (ATTN_ELEMS + (size_t)BATCH * TTXT)

__device__ __forceinline__ void gload_lds16(const float* g, float* l) {
  __builtin_amdgcn_global_load_lds(
      (const __attribute__((address_space(1))) void*)g,
      (__attribute__((address_space(3))) void*)l, 16, 0, 0);
}
__device__ __forceinline__ void gload_lds4(const float* g, float* l) {
  __builtin_amdgcn_global_load_lds(
      (const __attribute__((address_space(1))) void*)g,
      (__attribute__((address_space(3))) void*)l, 4, 0, 0);
}

#define VMCNT(n) asm volatile("s_waitcnt vmcnt(" #n ")" ::: "memory")
#define MEMFENCE asm volatile("" ::: "memory")

// ---------------------------------------------------------------------------
// Kernel P: W1[b,c,s] = m*exp(-2*logs), W2[b,c,s] = -0.5*exp(-2*logs)
// Written into the attn region of d_out (fully rewritten later by k_attn).
// ---------------------------------------------------------------------------
__global__ void k_prep(const float* __restrict__ m_p,
                       const float* __restrict__ logs_p,
                       float* __restrict__ w1, float* __restrict__ w2) {
  int gid = blockIdx.x * 256 + threadIdx.x;    // 0 .. 3,145,727
  float m = m_p[gid];
  float l = logs_p[gid];
  float r = __expf(-2.0f * l);
  w1[gid] = m * r;
  w2[gid] = -0.5f * r;
}

// ---------------------------------------------------------------------------
// Kernel A: cadd[b][s] = sum_c(-0.5*log(2pi) - logs) + sum_c(-0.5*m^2*r)
// ---------------------------------------------------------------------------
__global__ void k_cadd(const float* __restrict__ m_p,
                       const float* __restrict__ logs_p,
                       float* __restrict__ cadd) {
  int gid = blockIdx.x * 256 + threadIdx.x;        // 0 .. 16383
  int b = gid >> 9, s = gid & (TTXT - 1);
  const float* mp = m_p    + (size_t)b * CH * TTXT + s;
  const float* lp = logs_p + (size_t)b * CH * TTXT + s;
  float acc = -0.5f * 1.8378770664093453f * (float)CH;   // -C/2 * log(2*pi)
  #pragma unroll 4
  for (int c = 0; c < CH; ++c) {
    float l = lp[(size_t)c * TTXT];
    float m = mp[(size_t)c * TTXT];
    float r = __expf(-2.0f * l);
    acc -= l + 0.5f * m * m * r;
  }
  cadd[gid] = acc;
}

// ---------------------------------------------------------------------------
// Kernel B: neg[b,t,s] = sum_c z*(W1 + z*W2) + cadd[b,s]
// fp32 vector GEMM, 512 threads, acc[8][4]. Live set designed for the 64-VGPR
// allocation hipcc insists on (R4/R5 spill history in journal). R6: spill
// traffic gone, ~300us. UNCHANGED since R6.
// ---------------------------------------------------------------------------
#define BM 128
#define BN 128
#define BK 16

__global__ __launch_bounds__(512)
void k_gemm(const float* __restrict__ z_p,
            const float* __restrict__ w1g, const float* __restrict__ w2g,
            const float* __restrict__ cadd, float* __restrict__ neg) {
  __shared__ float Az[BK][BM];
  __shared__ float B1[BK][BN];
  __shared__ float B2[BK][BN];

  // chunked XCD swizzle (2048 blocks, 8 XCDs, 256 per chunk; bijective)
  int blk = (blockIdx.x & 7) * 256 + (blockIdx.x >> 3);
  int sb = blk & 3;            // TTXT/BN = 4
  int tb = (blk >> 2) & 15;    // TFEAT/BM = 16
  int b  = blk >> 6;
  int tid = threadIdx.x;
  int tx = tid & 31;           // col group: 4 cols at tx*4
  int ty = tid >> 5;           // row group: 8 rows at ty*8  (0..15)
  int wid  = tid >> 6;         // wave 0..7
  int lane = tid & 63;
  int lr = lane >> 5;          // row-within-pair
  int lc = (lane & 31) * 4;    // col (float4 granularity)

  const float* zb  = z_p + (size_t)b * CH * TFEAT + (size_t)tb * BM;
  const float* w1b = w1g + (size_t)b * CH * TTXT  + (size_t)sb * BN;
  const float* w2b = w2g + (size_t)b * CH * TTXT  + (size_t)sb * BN;

  float acc[8][4];
  #pragma unroll
  for (int i = 0; i < 8; ++i)
    #pragma unroll
    for (int j = 0; j < 4; ++j) acc[i][j] = 0.0f;

  for (int ko = 0; ko < CH / BK; ++ko) {
    int k0 = ko * BK;
    int kr = k0 + 2 * wid + lr;          // per-lane global k-row
    int kd = 2 * wid;                    // wave-uniform LDS row base
    gload_lds16(zb  + (size_t)kr * TFEAT + lc, &Az[kd][0]);
    gload_lds16(w1b + (size_t)kr * TTXT  + lc, &B1[kd][0]);
    gload_lds16(w2b + (size_t)kr * TTXT  + lc, &B2[kd][0]);
    __syncthreads();                     // drains vmcnt (loads landed)

    #pragma unroll
    for (int kk = 0; kk < BK; ++kk) {
      float4 a0 = *(const float4*)&Az[kk][ty * 8];
      float4 a1 = *(const float4*)&Az[kk][ty * 8 + 4];
      float4 p  = *(const float4*)&B1[kk][tx * 4];
      float4 q  = *(const float4*)&B2[kk][tx * 4];
      float a[8]   = {a0.x, a0.y, a0.z, a0.w, a1.x, a1.y, a1.z, a1.w};
      float w1v[4] = {p.x, p.y, p.z, p.w};
      float w2v[4] = {q.x, q.y, q.z, q.w};
      #pragma unroll
      for (int i = 0; i < 8; ++i)
        #pragma unroll
        for (int j = 0; j < 4; ++j)
          acc[i][j] = fmaf(a[i], fmaf(a[i], w2v[j], w1v[j]), acc[i][j]);
      __builtin_amdgcn_sched_barrier(0); // keep live set <= 64 VGPRs
    }
    __syncthreads();                     // tile consumed before restage
  }

  float4 cb4 = *(const float4*)(cadd + b * TTXT + sb * BN + tx * 4);
  float c0[4] = {cb4.x, cb4.y, cb4.z, cb4.w};
  float* ob = neg + (size_t)b * TFEAT * TTXT + (size_t)(tb * BM + ty * 8) * TTXT + sb * BN;
  #pragma unroll
  for (int i = 0; i < 8; ++i) {
    float4 o = {acc[i][0] + c0[0], acc[i][1] + c0[1], acc[i][2] + c0[2], acc[i][3] + c0[3]};
    *(float4*)(ob + (size_t)i * TTXT + tx * 4) = o;
  }
}

// ---------------------------------------------------------------------------
// Kernel C (R8 rewrite): row-parallel forward DP — 512 threads, x = tid.
// R6/R7 lesson: 1 wave/batch is ISSUE-bound (~600 cy/row solo). Now each
// thread owns ONE x: ~10 VALU/row/thread. prev[x-1] via DPP wave_shr:1
// in-wave + tiny double-buffered LDS boundary across waves + one raw
// s_barrier per row (manual lgkmcnt(0), no vmcnt drain -> staging pipeline
// survives). Decision bits = __ballot words. nf staged via ring-8 LDS rows
// (per-wave global_load_lds 4B, counted VMCNT(6)).
// Arithmetic per element identical to R1-R7 (bit-exact path).
// ---------------------------------------------------------------------------
__device__ __forceinline__ float dpp_shr1(float v) {
  return __int_as_float(__builtin_amdgcn_update_dpp(
      __float_as_int(v), __float_as_int(v), 0x138 /*wave_shr:1*/, 0xF, 0xF, false));
}

template<bool MASKED>
__device__ __forceinline__ float dp_row(float prev, int y, int tid, int lane, int w,
                                        float (*ring)[TTXT], unsigned (*bits)[16],
                                        float (*bndbuf)[12]) {
  float nf  = ring[y & 7][tid];
  float bnd = bndbuf[y & 1][w];          // neighbor wave's x-1 value (row y-1)
  float upd = dpp_shr1(prev);
  float up  = (lane == 0) ? bnd : upd;   // bndbuf[*][0] == NEGINF (x==0 edge)
  bool force = MASKED && (tid == y);
  bool gt = prev < up;
  unsigned long long m = __ballot(force || gt);
  if (w == 0) m &= ~1ull;                // x == 0 -> bit 0
  if (lane == 0) {
    bits[y][2 * w]     = (unsigned)m;
    bits[y][2 * w + 1] = (unsigned)(m >> 32);
  }
  float vc = force ? NEGINF : prev;
  float nv = fmaxf(vc, up) + nf;
  if (lane == 63) bndbuf[(y + 1) & 1][w + 1] = nv;
  asm volatile("s_waitcnt lgkmcnt(0)" ::: "memory");
  __builtin_amdgcn_s_barrier();
  MEMFENCE;                              // no LDS op crosses the barrier
  return nv;
}

__global__ __launch_bounds__(512, 1)
void k_dp(const float* __restrict__ neg, float* __restrict__ dur,
          int* __restrict__ idx_out, const float* __restrict__ x_mask) {
  __shared__ unsigned bits[TFEAT][16];   // 128 KiB  (bit x of row y)
  __shared__ float ring[8][TTXT];        //  16 KiB  (8-row nf ring)
  __shared__ float bndbuf[2][12];        // wave-boundary values, dbuf by row parity

  int b = blockIdx.x;
  int tid = threadIdx.x;
  int lane = tid & 63;
  int w = tid >> 6;                      // wave 0..7, x-range [64w, 64w+64)
  const float* nb = neg + (size_t)b * TFEAT * TTXT;

  if (tid < 24) ((float*)bndbuf)[tid] = NEGINF;

  // prologue: stage rows 0..5 (each wave its 64-float slice)
  #pragma unroll
  for (int y2 = 0; y2 < 6; ++y2)
    gload_lds4(nb + (size_t)y2 * TTXT + tid, &ring[y2][w * 64]);
  __syncthreads();                       // bndbuf init visible (drains vmcnt once; ok)

  // re-stage rows 0..5 are complete now (syncthreads drained); keep pipeline:
  float prev;
  {                                      // row 0 (y=0, masked)
    gload_lds4(nb + (size_t)6 * TTXT + tid, &ring[6][w * 64]);
    VMCNT(6);
    float nf = ring[0][tid];
    prev = (tid == 0) ? nf : (NEGINF + nf);   // max(-inf, 0/-inf) + nf, bit-exact
    if (lane == 0) { bits[0][2 * w] = 0u; bits[0][2 * w + 1] = 0u; }
    if (lane == 63) bndbuf[1][w + 1] = prev;
    asm volatile("s_waitcnt lgkmcnt(0)" ::: "memory");
    __builtin_amdgcn_s_barrier();
    MEMFENCE;
  }
  for (int y = 1; y < TTXT; ++y) {       // masked region (x==y force possible)
    gload_lds4(nb + (size_t)(y + 6) * TTXT + tid, &ring[(y + 6) & 7][w * 64]);
    VMCNT(6);
    prev = dp_row<true>(prev, y, tid, lane, w, ring, bits, bndbuf);
  }
  for (int y = TTXT; y <= TFEAT - 7; ++y) {   // light region
    gload_lds4(nb + (size_t)(y + 6) * TTXT + tid, &ring[(y + 6) & 7][w * 64]);
    VMCNT(6);
    prev = dp_row<false>(prev, y, tid, lane, w, ring, bits, bndbuf);
  }
  VMCNT(0);                              // tail rows already staged
  for (int y = TFEAT - 6; y < TFEAT; ++y)
    prev = dp_row<false>(prev, y, tid, lane, w, ring, bits, bndbuf);
  __syncthreads();

  // ---- serial backtrack (thread 0), 1-row-ahead word prefetch.
  if (tid == 0) {
    const float* xm = x_mask + (size_t)b * TTXT;
    int idx = TTXT - 1, cnt = 0;
    int W = idx >> 5;                    // 15
    unsigned cw = bits[TFEAT - 1][W];
    for (int y = TFEAT - 1; y >= 0; --y) {
      unsigned nc = 0, nl = 0;
      if (y > 0) { nc = bits[y - 1][W]; nl = (W > 0) ? bits[y - 1][W - 1] : 0; }
      idx_out[b * TFEAT + y] = idx;
      cnt++;
      if ((cw >> (idx & 31)) & 1u) {
        dur[b * TTXT + idx] = (float)cnt * xm[idx];
        cnt = 0;
        idx--;
      }
      int W2 = idx >> 5;
      if (W2 == W) cw = nc;
      else { W = W2; cw = nl; }          // word crossing (<=16 times)
    }
    dur[b * TTXT] = (float)cnt * xm[0];  // idx == 0 tail run
  }
}

// ---------------------------------------------------------------------------
// Kernel D: attn[b,y,x] = (x == idx[y]) * x_mask[b,x] * y_mask[b,y]
// ---------------------------------------------------------------------------
__global__ void k_attn(const int* __restrict__ idx_arr,
                       const float* __restrict__ x_mask,
                       const float* __restrict__ y_mask,
                       float* __restrict__ attn) {
  size_t gid = (size_t)blockIdx.x * 256 + threadIdx.x;
  size_t e = gid << 2;               // 4 floats per thread
  int b = (int)(e >> 20);            // TFEAT*TTXT = 2^20
  int rem = (int)(e & 1048575u);
  int y = rem >> 9;
  int x0 = rem & 511;
  int idx = idx_arr[b * TFEAT + y];
  float4 v = {0.f, 0.f, 0.f, 0.f};
  int d = idx - x0;
  if (d >= 0 && d < 4) {
    ((float*)&v)[d] = x_mask[b * TTXT + idx] * y_mask[b * TFEAT + y];
  }
  *(float4*)(attn + e) = v;
}

// ---------------------------------------------------------------------------
extern "C" void kernel_launch(void* const* d_in, const int* in_sizes, int n_in,
                              void* d_out, int out_size, void* d_ws, size_t ws_size,
                              hipStream_t stream) {
  const float* z_p    = (const float*)d_in[0];
  const float* m_p    = (const float*)d_in[1];
  const float* logs_p = (const float*)d_in[2];
  const float* x_mask = (const float*)d_in[3];
  const float* y_mask = (const float*)d_in[4];

  float* out  = (float*)d_out;
  float* attn = out;
  float* dur  = out + DUR_OFF;
  float* neg  = out + NEG_OFF;

  // W1/W2 scratch lives in the attn region (fully rewritten by k_attn later)
  float* w1s = attn;
  float* w2s = attn + (size_t)BATCH * CH * TTXT;      // 3,145,728 floats each

  // workspace: cadd (64 KiB) + idx array (256 KiB)
  float* cadd = (float*)d_ws;
  int*   idxa = (int*)((char*)d_ws + 65536);

  k_prep<<<(BATCH * CH * TTXT) / 256, 256, 0, stream>>>(m_p, logs_p, w1s, w2s);
  k_cadd<<<(BATCH * TTXT) / 256, 256, 0, stream>>>(m_p, logs_p, cadd);
  k_gemm<<<BATCH * (TFEAT / BM) * (TTXT / BN), 512, 0, stream>>>(z_p, w1s, w2s, cadd, neg);
  k_dp<<<BATCH, 512, 0, stream>>>(neg, dur, idxa, x_mask);
  k_attn<<<(int)(ATTN_ELEMS / 4 / 256), 256, 0, stream>>>(idxa, x_mask, y_mask, attn);
}

// Round 9
// 816.080 us; speedup vs baseline: 1.8367x; 1.8367x over previous
//
#include <hip/hip_runtime.h>
#include <math.h>

// Problem constants (fixed by the reference setup_inputs)
#define BATCH 32
#define CH    192
#define TFEAT 2048
#define TTXT  512
#define NEGINF (-1e9f)

#define ATTN_ELEMS ((size_t)BATCH * TFEAT * TTXT)   // 33,554,432
#define DUR_OFF    ATTN_ELEMS
#define NEG_OFF    (ATTN_ELEMS + (size_t)BATCH * TTXT)

__device__ __forceinline__ void gload_lds16(const float* g, float* l) {
  __builtin_amdgcn_global_load_lds(
      (const __attribute__((address_space(1))) void*)g,
      (__attribute__((address_space(3))) void*)l, 16, 0, 0);
}

// ---------------------------------------------------------------------------
// Kernel P: W1[b,c,s] = m*exp(-2*logs), W2[b,c,s] = -0.5*exp(-2*logs)
// Written into the attn region of d_out (fully rewritten later by k_attn).
// ---------------------------------------------------------------------------
__global__ void k_prep(const float* __restrict__ m_p,
                       const float* __restrict__ logs_p,
                       float* __restrict__ w1, float* __restrict__ w2) {
  int gid = blockIdx.x * 256 + threadIdx.x;    // 0 .. 3,145,727
  float m = m_p[gid];
  float l = logs_p[gid];
  float r = __expf(-2.0f * l);
  w1[gid] = m * r;
  w2[gid] = -0.5f * r;
}

// ---------------------------------------------------------------------------
// Kernel A: cadd[b][s] = sum_c(-0.5*log(2pi) - logs) + sum_c(-0.5*m^2*r)
// ---------------------------------------------------------------------------
__global__ void k_cadd(const float* __restrict__ m_p,
                       const float* __restrict__ logs_p,
                       float* __restrict__ cadd) {
  int gid = blockIdx.x * 256 + threadIdx.x;        // 0 .. 16383
  int b = gid >> 9, s = gid & (TTXT - 1);
  const float* mp = m_p    + (size_t)b * CH * TTXT + s;
  const float* lp = logs_p + (size_t)b * CH * TTXT + s;
  float acc = -0.5f * 1.8378770664093453f * (float)CH;   // -C/2 * log(2*pi)
  #pragma unroll 4
  for (int c = 0; c < CH; ++c) {
    float l = lp[(size_t)c * TTXT];
    float m = mp[(size_t)c * TTXT];
    float r = __expf(-2.0f * l);
    acc -= l + 0.5f * m * m * r;
  }
  cadd[gid] = acc;
}

// ---------------------------------------------------------------------------
// Kernel B: neg[b,t,s] = sum_c z*(W1 + z*W2) + cadd[b,s]
// fp32 vector GEMM, 512 threads, acc[8][4]. Live set designed for the 64-VGPR
// allocation hipcc insists on (R4/R5 spill history). UNCHANGED since R6.
// ---------------------------------------------------------------------------
#define BM 128
#define BN 128
#define BK 16

__global__ __launch_bounds__(512)
void k_gemm(const float* __restrict__ z_p,
            const float* __restrict__ w1g, const float* __restrict__ w2g,
            const float* __restrict__ cadd, float* __restrict__ neg) {
  __shared__ float Az[BK][BM];
  __shared__ float B1[BK][BN];
  __shared__ float B2[BK][BN];

  // chunked XCD swizzle (2048 blocks, 8 XCDs, 256 per chunk; bijective)
  int blk = (blockIdx.x & 7) * 256 + (blockIdx.x >> 3);
  int sb = blk & 3;            // TTXT/BN = 4
  int tb = (blk >> 2) & 15;    // TFEAT/BM = 16
  int b  = blk >> 6;
  int tid = threadIdx.x;
  int tx = tid & 31;           // col group: 4 cols at tx*4
  int ty = tid >> 5;           // row group: 8 rows at ty*8  (0..15)
  int wid  = tid >> 6;         // wave 0..7
  int lane = tid & 63;
  int lr = lane >> 5;          // row-within-pair
  int lc = (lane & 31) * 4;    // col (float4 granularity)

  const float* zb  = z_p + (size_t)b * CH * TFEAT + (size_t)tb * BM;
  const float* w1b = w1g + (size_t)b * CH * TTXT  + (size_t)sb * BN;
  const float* w2b = w2g + (size_t)b * CH * TTXT  + (size_t)sb * BN;

  float acc[8][4];
  #pragma unroll
  for (int i = 0; i < 8; ++i)
    #pragma unroll
    for (int j = 0; j < 4; ++j) acc[i][j] = 0.0f;

  for (int ko = 0; ko < CH / BK; ++ko) {
    int k0 = ko * BK;
    int kr = k0 + 2 * wid + lr;          // per-lane global k-row
    int kd = 2 * wid;                    // wave-uniform LDS row base
    gload_lds16(zb  + (size_t)kr * TFEAT + lc, &Az[kd][0]);
    gload_lds16(w1b + (size_t)kr * TTXT  + lc, &B1[kd][0]);
    gload_lds16(w2b + (size_t)kr * TTXT  + lc, &B2[kd][0]);
    __syncthreads();                     // drains vmcnt (loads landed)

    #pragma unroll
    for (int kk = 0; kk < BK; ++kk) {
      float4 a0 = *(const float4*)&Az[kk][ty * 8];
      float4 a1 = *(const float4*)&Az[kk][ty * 8 + 4];
      float4 p  = *(const float4*)&B1[kk][tx * 4];
      float4 q  = *(const float4*)&B2[kk][tx * 4];
      float a[8]   = {a0.x, a0.y, a0.z, a0.w, a1.x, a1.y, a1.z, a1.w};
      float w1v[4] = {p.x, p.y, p.z, p.w};
      float w2v[4] = {q.x, q.y, q.z, q.w};
      #pragma unroll
      for (int i = 0; i < 8; ++i)
        #pragma unroll
        for (int j = 0; j < 4; ++j)
          acc[i][j] = fmaf(a[i], fmaf(a[i], w2v[j], w1v[j]), acc[i][j]);
      __builtin_amdgcn_sched_barrier(0); // keep live set <= 64 VGPRs
    }
    __syncthreads();                     // tile consumed before restage
  }

  float4 cb4 = *(const float4*)(cadd + b * TTXT + sb * BN + tx * 4);
  float c0[4] = {cb4.x, cb4.y, cb4.z, cb4.w};
  float* ob = neg + (size_t)b * TFEAT * TTXT + (size_t)(tb * BM + ty * 8) * TTXT + sb * BN;
  #pragma unroll
  for (int i = 0; i < 8; ++i) {
    float4 o = {acc[i][0] + c0[0], acc[i][1] + c0[1], acc[i][2] + c0[2], acc[i][3] + c0[3]};
    *(float4*)(ob + (size_t)i * TTXT + tx * 4) = o;
  }
}

// ---------------------------------------------------------------------------
// Kernel C (R9): SKEWED-WAVEFRONT DP. 8 waves, x = tid; wave w processes
// 16-row window i at phase p = w + i (wave w runs 16 rows behind wave w-1).
// Cross-wave boundary values land one phase earlier -> ONE barrier per 16
// rows (136 total; R8 paid a barrier+drain per row = 1230cy/row).
// nf loaded straight to registers (A/B double-buffer, per-wave parity
// rotation, static indexing); bnd via triple-buffered 1.5KB LDS + readlane.
// Arithmetic per element identical to R8 (which passed) -> bit-exact path.
// ---------------------------------------------------------------------------
#define KROWS 16
#define NWIN  (TFEAT / KROWS)     // 128 windows
#define NMASKW (TTXT / KROWS)     // 32 masked windows

__device__ __forceinline__ float dpp_shr1(float v) {
  return __int_as_float(__builtin_amdgcn_update_dpp(
      __float_as_int(v), __float_as_int(v), 0x138 /*wave_shr:1*/, 0xF, 0xF, false));
}

template<bool MASKED>
__device__ __forceinline__ void dp_rows16(
    float& prev, const float (&cur)[KROWS], float bndv,
    int y0, int tid, int lane, int w, bool first,
    unsigned long long (*bitsq)[8], float (*bnd)[8][16], int slotW) {
  #pragma unroll
  for (int r = 0; r < KROWS; ++r) {
    float upd = dpp_shr1(prev);
    float bnd_r = __int_as_float(__builtin_amdgcn_readlane(
        __float_as_int(bndv), (r == 0) ? 15 : (r - 1)));
    float l0 = (w > 0) ? bnd_r : ((first && r == 0) ? 0.0f : NEGINF);
    float up = (lane == 0) ? l0 : upd;
    bool force = MASKED && (tid == y0 + r);
    bool gt = prev < up;
    unsigned long long m = __ballot(force || gt);
    if (w == 0) m &= ~1ull;              // x == 0 never moves
    if (lane == 0) bitsq[y0 + r][w] = m;
    float vc = force ? NEGINF : prev;
    prev = fmaxf(vc, up) + cur[r];
    if (lane == 63) bnd[slotW][w][r] = prev;   // boundary for wave w+1
  }
}

__device__ __forceinline__ void dp_phase(
    int p, float (&cur)[KROWS], float (&nxt)[KROWS],
    float& prev, const float* nb, int tid, int lane, int w,
    unsigned long long (*bitsq)[8], float (*bnd)[8][16]) {
  int i = p - w;                         // this wave's window this phase
  int j = i + 1;                         // window to prefetch
  if (j >= 1 && j < NWIN) {
    const float* base = nb + (size_t)(j * KROWS) * TTXT + tid;
    #pragma unroll
    for (int r = 0; r < KROWS; ++r) nxt[r] = base[(size_t)r * TTXT];
  }
  __builtin_amdgcn_sched_barrier(0);     // loads issued before compute
  if (i >= 0 && i < NWIN) {
    float bndv = NEGINF;
    if (w > 0) {
      int sl = lane & 15;                // lanes 0..14: rows y0..y0+14 of w-1;
      bndv = (sl < 15) ? bnd[i % 3][w - 1][sl]          // lane 15: row y0-1
                       : bnd[(i + 2) % 3][w - 1][15];
    }
    int y0 = i * KROWS;
    bool first = (w == 0) && (i == 0);
    if (i < NMASKW)
      dp_rows16<true >(prev, cur, bndv, y0, tid, lane, w, first, bitsq, bnd, i % 3);
    else
      dp_rows16<false>(prev, cur, bndv, y0, tid, lane, w, first, bitsq, bnd, i % 3);
  }
  asm volatile("s_waitcnt lgkmcnt(0)" ::: "memory");   // bits/bnd writes drained
  __builtin_amdgcn_s_barrier();
  __builtin_amdgcn_sched_barrier(0);
}

__global__ __launch_bounds__(512, 1)
void k_dp(const float* __restrict__ neg, float* __restrict__ dur,
          int* __restrict__ idx_out, const float* __restrict__ x_mask) {
  __shared__ unsigned long long bitsq[TFEAT][8];   // 128 KiB decision bits
  __shared__ float bnd[3][8][16];                  // 1.5 KiB boundary ring
  int b = blockIdx.x, tid = threadIdx.x;
  int lane = tid & 63, w = tid >> 6;
  const float* nb = neg + (size_t)b * TFEAT * TTXT;

  if (tid < 3 * 8 * 16) ((float*)bnd)[tid] = NEGINF;

  float A[KROWS], B[KROWS];
  {                                      // prologue: window 0 -> A (all waves)
    const float* base = nb + tid;
    #pragma unroll
    for (int r = 0; r < KROWS; ++r) A[r] = base[(size_t)r * TTXT];
  }
  __syncthreads();

  float prev = NEGINF;
  // per-wave parity rotation keeps nf-set indexing static (window i -> A if
  // i even else B; cur at phase p has parity (p-w)&1)
  if ((w & 1) == 0) {
    for (int p = 0; p < NWIN + 8; p += 2) {
      dp_phase(p,     A, B, prev, nb, tid, lane, w, bitsq, bnd);
      dp_phase(p + 1, B, A, prev, nb, tid, lane, w, bitsq, bnd);
    }
  } else {
    for (int p = 0; p < NWIN + 8; p += 2) {
      dp_phase(p,     B, A, prev, nb, tid, lane, w, bitsq, bnd);
      dp_phase(p + 1, A, B, prev, nb, tid, lane, w, bitsq, bnd);
    }
  }
  __syncthreads();

  // ---- serial backtrack (tid 0) with 8-row-ahead register ring: words
  // {W, W-1} of row y-8 prefetched at row y (idx drifts <= 8 -> always covered)
  if (tid == 0) {
    const float* xm = x_mask + (size_t)b * TTXT;
    const unsigned* bw = (const unsigned*)bitsq;   // [TFEAT][16] u32 view
    int idx = TTXT - 1, cnt = 0;
    unsigned uc[8], ul[8]; int wi[8];
    #pragma unroll
    for (int q = 0; q < 8; ++q) {        // rows 2040..2047 (slot q = y&7)
      uc[q] = bw[(2040 + q) * 16 + 15];
      ul[q] = bw[(2040 + q) * 16 + 14];
      wi[q] = 15;
    }
    for (int yb = 2040; yb >= 8; yb -= 8) {
      #pragma unroll
      for (int jj = 7; jj >= 0; --jj) {
        int y = yb + jj;                 // slot = jj (yb % 8 == 0)
        unsigned word = ((idx >> 5) == wi[jj]) ? uc[jj] : ul[jj];
        idx_out[b * TFEAT + y] = idx;
        cnt++;
        if ((word >> (idx & 31)) & 1u) {
          dur[b * TTXT + idx] = (float)cnt * xm[idx];
          cnt = 0; idx--;
        }
        int W = idx >> 5;                // refill slot jj for row y-8
        uc[jj] = bw[(y - 8) * 16 + W];
        ul[jj] = (W > 0) ? bw[(y - 8) * 16 + W - 1] : 0u;
        wi[jj] = W;
      }
    }
    #pragma unroll
    for (int jj = 7; jj >= 0; --jj) {    // tail rows 7..0
      int y = jj;
      unsigned word = ((idx >> 5) == wi[jj]) ? uc[jj] : ul[jj];
      idx_out[b * TFEAT + y] = idx;
      cnt++;
      if ((word >> (idx & 31)) & 1u) {
        dur[b * TTXT + idx] = (float)cnt * xm[idx];
        cnt = 0; idx--;
      }
    }
    dur[b * TTXT] = (float)cnt * xm[0];  // idx == 0 tail run
  }
}

// ---------------------------------------------------------------------------
// Kernel D: attn[b,y,x] = (x == idx[y]) * x_mask[b,x] * y_mask[b,y]
// ---------------------------------------------------------------------------
__global__ void k_attn(const int* __restrict__ idx_arr,
                       const float* __restrict__ x_mask,
                       const float* __restrict__ y_mask,
                       float* __restrict__ attn) {
  size_t gid = (size_t)blockIdx.x * 256 + threadIdx.x;
  size_t e = gid << 2;               // 4 floats per thread
  int b = (int)(e >> 20);            // TFEAT*TTXT = 2^20
  int rem = (int)(e & 1048575u);
  int y = rem >> 9;
  int x0 = rem & 511;
  int idx = idx_arr[b * TFEAT + y];
  float4 v = {0.f, 0.f, 0.f, 0.f};
  int d = idx - x0;
  if (d >= 0 && d < 4) {
    ((float*)&v)[d] = x_mask[b * TTXT + idx] * y_mask[b * TFEAT + y];
  }
  *(float4*)(attn + e) = v;
}

// ---------------------------------------------------------------------------
extern "C" void kernel_launch(void* const* d_in, const int* in_sizes, int n_in,
                              void* d_out, int out_size, void* d_ws, size_t ws_size,
                              hipStream_t stream) {
  const float* z_p    = (const float*)d_in[0];
  const float* m_p    = (const float*)d_in[1];
  const float* logs_p = (const float*)d_in[2];
  const float* x_mask = (const float*)d_in[3];
  const float* y_mask = (const float*)d_in[4];

  float* out  = (float*)d_out;
  float* attn = out;
  float* dur  = out + DUR_OFF;
  float* neg  = out + NEG_OFF;

  // W1/W2 scratch lives in the attn region (fully rewritten by k_attn later)
  float* w1s = attn;
  float* w2s = attn + (size_t)BATCH * CH * TTXT;      // 3,145,728 floats each

  // workspace: cadd (64 KiB) + idx array (256 KiB)
  float* cadd = (float*)d_ws;
  int*   idxa = (int*)((char*)d_ws + 65536);

  k_prep<<<(BATCH * CH * TTXT) / 256, 256, 0, stream>>>(m_p, logs_p, w1s, w2s);
  k_cadd<<<(BATCH * TTXT) / 256, 256, 0, stream>>>(m_p, logs_p, cadd);
  k_gemm<<<BATCH * (TFEAT / BM) * (TTXT / BN), 512, 0, stream>>>(z_p, w1s, w2s, cadd, neg);
  k_dp<<<BATCH, 512, 0, stream>>>(neg, dur, idxa, x_mask);
  k_attn<<<(int)(ATTN_ELEMS / 4 / 256), 256, 0, stream>>>(idxa, x_mask, y_mask, attn);
}

// Round 11
// 782.691 us; speedup vs baseline: 1.9151x; 1.0427x over previous
//
#include <hip/hip_runtime.h>
#include <math.h>

// Problem constants (fixed by the reference setup_inputs)
#define BATCH 32
#define CH    192
#define TFEAT 2048
#define TTXT  512
#define NEGINF (-1e9f)

#define ATTN_ELEMS ((size_t)BATCH * TFEAT * TTXT)   // 33,554,432
#define DUR_OFF    ATTN_ELEMS
#define NEG_OFF    (ATTN_ELEMS + (size_t)BATCH * TTXT)

__device__ __forceinline__ void gload_lds16(const float* g, float* l) {
  __builtin_amdgcn_global_load_lds(
      (const __attribute__((address_space(1))) void*)g,
      (__attribute__((address_space(3))) void*)l, 16, 0, 0);
}

#define VMCNT(n) asm volatile("s_waitcnt vmcnt(" #n ")" ::: "memory")

// ---------------------------------------------------------------------------
// Kernel P: W1[b,c,s] = m*exp(-2*logs), W2[b,c,s] = -0.5*exp(-2*logs)
// Written into the attn region of d_out (fully rewritten later by k_attn).
// ---------------------------------------------------------------------------
__global__ void k_prep(const float* __restrict__ m_p,
                       const float* __restrict__ logs_p,
                       float* __restrict__ w1, float* __restrict__ w2) {
  int gid = blockIdx.x * 256 + threadIdx.x;    // 0 .. 3,145,727
  float m = m_p[gid];
  float l = logs_p[gid];
  float r = __expf(-2.0f * l);
  w1[gid] = m * r;
  w2[gid] = -0.5f * r;
}

// ---------------------------------------------------------------------------
// Kernel A: cadd[b][s] = sum_c(-0.5*log(2pi) - logs) + sum_c(-0.5*m^2*r)
// ---------------------------------------------------------------------------
__global__ void k_cadd(const float* __restrict__ m_p,
                       const float* __restrict__ logs_p,
                       float* __restrict__ cadd) {
  int gid = blockIdx.x * 256 + threadIdx.x;        // 0 .. 16383
  int b = gid >> 9, s = gid & (TTXT - 1);
  const float* mp = m_p    + (size_t)b * CH * TTXT + s;
  const float* lp = logs_p + (size_t)b * CH * TTXT + s;
  float acc = -0.5f * 1.8378770664093453f * (float)CH;   // -C/2 * log(2*pi)
  #pragma unroll 4
  for (int c = 0; c < CH; ++c) {
    float l = lp[(size_t)c * TTXT];
    float m = mp[(size_t)c * TTXT];
    float r = __expf(-2.0f * l);
    acc -= l + 0.5f * m * m * r;
  }
  cadd[gid] = acc;
}

// ---------------------------------------------------------------------------
// Kernel B: neg[b,t,s] = sum_c z*(W1 + z*W2) + cadd[b,s]
// fp32 vector GEMM, 512 threads, acc[8][4] (64-VGPR live-set design — R4/R5
// spill history). T3-minimum 2-phase LDS double-buffer — STAGE(next) issued
// BEFORE compute, one vmcnt(0)+raw barrier per tile (was: full drain exposed
// every ko). Same ko/kk/fma order -> neg bit-identical to R6-R9.
// ---------------------------------------------------------------------------
#define BM 128
#define BN 128
#define BK 16

__global__ __launch_bounds__(512)
void k_gemm(const float* __restrict__ z_p,
            const float* __restrict__ w1g, const float* __restrict__ w2g,
            const float* __restrict__ cadd, float* __restrict__ neg) {
  __shared__ float Az[2][BK][BM];
  __shared__ float B1[2][BK][BN];
  __shared__ float B2[2][BK][BN];

  // chunked XCD swizzle (2048 blocks, 8 XCDs, 256 per chunk; bijective)
  int blk = (blockIdx.x & 7) * 256 + (blockIdx.x >> 3);
  int sb = blk & 3;            // TTXT/BN = 4
  int tb = (blk >> 2) & 15;    // TFEAT/BM = 16
  int b  = blk >> 6;
  int tid = threadIdx.x;
  int tx = tid & 31;           // col group: 4 cols at tx*4
  int ty = tid >> 5;           // row group: 8 rows at ty*8  (0..15)
  int wid  = tid >> 6;         // wave 0..7
  int lane = tid & 63;
  int lr = lane >> 5;          // row-within-pair
  int lc = (lane & 31) * 4;    // col (float4 granularity)

  const float* zb  = z_p + (size_t)b * CH * TFEAT + (size_t)tb * BM;
  const float* w1b = w1g + (size_t)b * CH * TTXT  + (size_t)sb * BN;
  const float* w2b = w2g + (size_t)b * CH * TTXT  + (size_t)sb * BN;

  auto STAGE = [&](int buf, int ko) {
    int kr = ko * BK + 2 * wid + lr;     // per-lane global k-row
    int kd = 2 * wid;                    // wave-uniform LDS row base
    gload_lds16(zb  + (size_t)kr * TFEAT + lc, &Az[buf][kd][0]);
    gload_lds16(w1b + (size_t)kr * TTXT  + lc, &B1[buf][kd][0]);
    gload_lds16(w2b + (size_t)kr * TTXT  + lc, &B2[buf][kd][0]);
  };

  float acc[8][4];
  #pragma unroll
  for (int i = 0; i < 8; ++i)
    #pragma unroll
    for (int j = 0; j < 4; ++j) acc[i][j] = 0.0f;

  STAGE(0, 0);
  VMCNT(0);
  __builtin_amdgcn_s_barrier();

  for (int ko = 0; ko < CH / BK; ++ko) {
    int cur = ko & 1;
    if (ko + 1 < CH / BK) STAGE(cur ^ 1, ko + 1);   // prefetch next tile

    #pragma unroll
    for (int kk = 0; kk < BK; ++kk) {
      float4 a0 = *(const float4*)&Az[cur][kk][ty * 8];
      float4 a1 = *(const float4*)&Az[cur][kk][ty * 8 + 4];
      float4 p  = *(const float4*)&B1[cur][kk][tx * 4];
      float4 q  = *(const float4*)&B2[cur][kk][tx * 4];
      float a[8]   = {a0.x, a0.y, a0.z, a0.w, a1.x, a1.y, a1.z, a1.w};
      float w1v[4] = {p.x, p.y, p.z, p.w};
      float w2v[4] = {q.x, q.y, q.z, q.w};
      #pragma unroll
      for (int i = 0; i < 8; ++i)
        #pragma unroll
        for (int j = 0; j < 4; ++j)
          acc[i][j] = fmaf(a[i], fmaf(a[i], w2v[j], w1v[j]), acc[i][j]);
      __builtin_amdgcn_sched_barrier(0); // keep live set <= 64 VGPRs
    }
    VMCNT(0);                            // next tile landed (had whole compute)
    __builtin_amdgcn_s_barrier();
  }

  float4 cb4 = *(const float4*)(cadd + b * TTXT + sb * BN + tx * 4);
  float c0[4] = {cb4.x, cb4.y, cb4.z, cb4.w};
  float* ob = neg + (size_t)b * TFEAT * TTXT + (size_t)(tb * BM + ty * 8) * TTXT + sb * BN;
  #pragma unroll
  for (int i = 0; i < 8; ++i) {
    float4 o = {acc[i][0] + c0[0], acc[i][1] + c0[1], acc[i][2] + c0[2], acc[i][3] + c0[3]};
    *(float4*)(ob + (size_t)i * TTXT + tx * 4) = o;
  }
}

// ---------------------------------------------------------------------------
// Kernel C (R11): skewed-wavefront DP, lean row body — writelane-free.
// R10's __builtin_amdgcn_writelane doesn't exist on this toolchain; ballot
// and readlane(prev,63) are wave-uniform, so per-row keeps are uniform
// selects: keep = (lane==r) ? val : keep (v_cmp + cndmask, no exec toggles).
// Boundary readlanes hoisted to window start (s_bnd[16] SGPRs); ONE
// if(lane<16) LDS write block per 16-row window. Row chain:
// dpp -> cndmask -> fmax -> add. Arithmetic identical to R8/R9 (bit-exact).
// ---------------------------------------------------------------------------
#define KROWS 16
#define NWIN  (TFEAT / KROWS)     // 128 windows
#define NMASKW (TTXT / KROWS)     // 32 masked windows

__device__ __forceinline__ float dpp_shr1(float v) {
  return __int_as_float(__builtin_amdgcn_update_dpp(
      __float_as_int(v), __float_as_int(v), 0x138 /*wave_shr:1*/, 0xF, 0xF, false));
}

template<bool MASKED>
__device__ __forceinline__ void dp_win16(
    float& prev, const float (&cur)[KROWS], const float (&s_bnd)[KROWS],
    int y0, int tid, int lane, int w,
    unsigned long long (*bitsq)[8], float (*bndlds)[8][KROWS], int slot) {
  unsigned keep_lo = 0, keep_hi = 0;
  float bkeep = 0.0f;
  unsigned long long andm = (w == 0) ? ~1ull : ~0ull;   // x==0 never moves
  #pragma unroll
  for (int r = 0; r < KROWS; ++r) {
    float upd = dpp_shr1(prev);
    float up = (lane == 0) ? s_bnd[r] : upd;
    bool force = MASKED && (tid == y0 + r);
    bool gt = prev < up;
    unsigned long long m = __ballot(force || gt) & andm;  // uniform (SGPR pair)
    bool mine = (lane == r);
    keep_lo = mine ? (unsigned)m : keep_lo;
    keep_hi = mine ? (unsigned)(m >> 32) : keep_hi;
    float vc = force ? NEGINF : prev;
    prev = fmaxf(vc, up) + cur[r];
    float v63 = __int_as_float(
        __builtin_amdgcn_readlane(__float_as_int(prev), 63));  // uniform
    bkeep = mine ? v63 : bkeep;
  }
  if (lane < KROWS) {                    // one exec toggle per window
    bndlds[slot][w][lane] = bkeep;
    bitsq[y0 + lane][w] =
        ((unsigned long long)keep_hi << 32) | keep_lo;
  }
}

__device__ __forceinline__ void dp_phase(
    int p, float (&cur)[KROWS], float (&nxt)[KROWS],
    float& prev, const float* nb, int tid, int lane, int w,
    unsigned long long (*bitsq)[8], float (*bndlds)[8][KROWS]) {
  int i = p - w;                         // this wave's window this phase
  int j = i + 1;                         // window to prefetch
  if (j >= 1 && j < NWIN) {
    const float* base = nb + (size_t)(j * KROWS) * TTXT + tid;
    #pragma unroll
    for (int r = 0; r < KROWS; ++r) nxt[r] = base[(size_t)r * TTXT];
  }
  __builtin_amdgcn_sched_barrier(0);     // loads issued before compute
  if (i >= 0 && i < NWIN) {
    float s_bnd[KROWS];                  // hoisted boundary values (SGPRs)
    if (w > 0) {
      float v   = bndlds[i % 3][w - 1][lane & 15];
      float v15 = bndlds[(i + 2) % 3][w - 1][15];
      s_bnd[0] = __int_as_float(__builtin_amdgcn_readfirstlane(__float_as_int(v15)));
      #pragma unroll
      for (int r = 1; r < KROWS; ++r)
        s_bnd[r] = __int_as_float(__builtin_amdgcn_readlane(__float_as_int(v), r - 1));
    } else {
      #pragma unroll
      for (int r = 0; r < KROWS; ++r) s_bnd[r] = NEGINF;
      if (i == 0) s_bnd[0] = 0.0f;       // y==0, x==0 edge
    }
    int y0 = i * KROWS;
    if (i < NMASKW) dp_win16<true >(prev, cur, s_bnd, y0, tid, lane, w, bitsq, bndlds, i % 3);
    else            dp_win16<false>(prev, cur, s_bnd, y0, tid, lane, w, bitsq, bndlds, i % 3);
  }
  asm volatile("s_waitcnt lgkmcnt(0)" ::: "memory");   // window writes drained
  __builtin_amdgcn_s_barrier();
  __builtin_amdgcn_sched_barrier(0);
}

__global__ __launch_bounds__(512, 1)
void k_dp(const float* __restrict__ neg, float* __restrict__ dur,
          int* __restrict__ idx_out, const float* __restrict__ x_mask) {
  __shared__ unsigned long long bitsq[TFEAT][8];   // 128 KiB decision bits
  __shared__ float bndlds[3][8][KROWS];            // 1.5 KiB boundary ring
  int b = blockIdx.x, tid = threadIdx.x;
  int lane = tid & 63, w = tid >> 6;
  const float* nb = neg + (size_t)b * TFEAT * TTXT;

  if (tid < 3 * 8 * KROWS) ((float*)bndlds)[tid] = NEGINF;

  float A[KROWS], B[KROWS];
  {                                      // prologue: window 0 -> A (all waves)
    const float* base = nb + tid;
    #pragma unroll
    for (int r = 0; r < KROWS; ++r) A[r] = base[(size_t)r * TTXT];
  }
  __syncthreads();

  float prev = NEGINF;
  // per-wave parity rotation keeps nf-buffer indexing static
  if ((w & 1) == 0) {
    for (int p = 0; p < NWIN + 8; p += 2) {
      dp_phase(p,     A, B, prev, nb, tid, lane, w, bitsq, bndlds);
      dp_phase(p + 1, B, A, prev, nb, tid, lane, w, bitsq, bndlds);
    }
  } else {
    for (int p = 0; p < NWIN + 8; p += 2) {
      dp_phase(p,     B, A, prev, nb, tid, lane, w, bitsq, bndlds);
      dp_phase(p + 1, A, B, prev, nb, tid, lane, w, bitsq, bndlds);
    }
  }
  __syncthreads();

  // ---- serial backtrack (tid 0) with 8-row-ahead register ring: words
  // {W, W-1} of row y-8 prefetched at row y (idx drifts <= 8 -> always covered)
  if (tid == 0) {
    const float* xm = x_mask + (size_t)b * TTXT;
    const unsigned* bw = (const unsigned*)bitsq;   // [TFEAT][16] u32 view
    int idx = TTXT - 1, cnt = 0;
    unsigned uc[8], ul[8]; int wi[8];
    #pragma unroll
    for (int q = 0; q < 8; ++q) {        // rows 2040..2047 (slot q = y&7)
      uc[q] = bw[(2040 + q) * 16 + 15];
      ul[q] = bw[(2040 + q) * 16 + 14];
      wi[q] = 15;
    }
    for (int yb = 2040; yb >= 8; yb -= 8) {
      #pragma unroll
      for (int jj = 7; jj >= 0; --jj) {
        int y = yb + jj;                 // slot = jj (yb % 8 == 0)
        unsigned word = ((idx >> 5) == wi[jj]) ? uc[jj] : ul[jj];
        idx_out[b * TFEAT + y] = idx;
        cnt++;
        if ((word >> (idx & 31)) & 1u) {
          dur[b * TTXT + idx] = (float)cnt * xm[idx];
          cnt = 0; idx--;
        }
        int W = idx >> 5;                // refill slot jj for row y-8
        uc[jj] = bw[(y - 8) * 16 + W];
        ul[jj] = (W > 0) ? bw[(y - 8) * 16 + W - 1] : 0u;
        wi[jj] = W;
      }
    }
    #pragma unroll
    for (int jj = 7; jj >= 0; --jj) {    // tail rows 7..0
      int y = jj;
      unsigned word = ((idx >> 5) == wi[jj]) ? uc[jj] : ul[jj];
      idx_out[b * TFEAT + y] = idx;
      cnt++;
      if ((word >> (idx & 31)) & 1u) {
        dur[b * TTXT + idx] = (float)cnt * xm[idx];
        cnt = 0; idx--;
      }
    }
    dur[b * TTXT] = (float)cnt * xm[0];  // idx == 0 tail run
  }
}

// ---------------------------------------------------------------------------
// Kernel D: attn[b,y,x] = (x == idx[y]) * x_mask[b,x] * y_mask[b,y]
// ---------------------------------------------------------------------------
__global__ void k_attn(const int* __restrict__ idx_arr,
                       const float* __restrict__ x_mask,
                       const float* __restrict__ y_mask,
                       float* __restrict__ attn) {
  size_t gid = (size_t)blockIdx.x * 256 + threadIdx.x;
  size_t e = gid << 2;               // 4 floats per thread
  int b = (int)(e >> 20);            // TFEAT*TTXT = 2^20
  int rem = (int)(e & 1048575u);
  int y = rem >> 9;
  int x0 = rem & 511;
  int idx = idx_arr[b * TFEAT + y];
  float4 v = {0.f, 0.f, 0.f, 0.f};
  int d = idx - x0;
  if (d >= 0 && d < 4) {
    ((float*)&v)[d] = x_mask[b * TTXT + idx] * y_mask[b * TFEAT + y];
  }
  *(float4*)(attn + e) = v;
}

// ---------------------------------------------------------------------------
extern "C" void kernel_launch(void* const* d_in, const int* in_sizes, int n_in,
                              void* d_out, int out_size, void* d_ws, size_t ws_size,
                              hipStream_t stream) {
  const float* z_p    = (const float*)d_in[0];
  const float* m_p    = (const float*)d_in[1];
  const float* logs_p = (const float*)d_in[2];
  const float* x_mask = (const float*)d_in[3];
  const float* y_mask = (const float*)d_in[4];

  float* out  = (float*)d_out;
  float* attn = out;
  float* dur  = out + DUR_OFF;
  float* neg  = out + NEG_OFF;

  // W1/W2 scratch lives in the attn region (fully rewritten by k_attn later)
  float* w1s = attn;
  float* w2s = attn + (size_t)BATCH * CH * TTXT;      // 3,145,728 floats each

  // workspace: cadd (64 KiB) + idx array (256 KiB)
  float* cadd = (float*)d_ws;
  int*   idxa = (int*)((char*)d_ws + 65536);

  k_prep<<<(BATCH * CH * TTXT) / 256, 256, 0, stream>>>(m_p, logs_p, w1s, w2s);
  k_cadd<<<(BATCH * TTXT) / 256, 256, 0, stream>>>(m_p, logs_p, cadd);
  k_gemm<<<BATCH * (TFEAT / BM) * (TTXT / BN), 512, 0, stream>>>(z_p, w1s, w2s, cadd, neg);
  k_dp<<<BATCH, 512, 0, stream>>>(neg, dur, idxa, x_mask);
  k_attn<<<(int)(ATTN_ELEMS / 4 / 256), 256, 0, stream>>>(idxa, x_mask, y_mask, attn);
}